// Round 8
// baseline (147.541 us; speedup 1.0000x reference)
//
#include <hip/hip_runtime.h>
#include <hip/hip_cooperative_groups.h>
#include <stdint.h>

namespace cg = cooperative_groups;

#define HH 512
#define WW 512
#define HW (HH * WW)          // 262144 pixels per image
#define WPR 8                 // u64 words per row (global layout)
#define NWORDS (HH * WPR)     // 4096 words per image
#define NB 16                 // batch
#define NIMG (2 * NB)         // 32 masks

typedef unsigned long long u64;

// Zhang-Suen sub-step core on prebuilt neighbor views (bit k = pixel col k).
__device__ __forceinline__ u64 zs_core(u64 cc, u64 P2, u64 P3, u64 P4, u64 P5,
                                       u64 P6, u64 P7, u64 P8, u64 P9, int step) {
    u64 ab = P2 ^ P3;
    u64 s1 = ab ^ P4, c1 = (P2 & P3) | (ab & P4);
    u64 de = P5 ^ P6;
    u64 s2 = de ^ P7, c2 = (P5 & P6) | (de & P7);
    u64 s3 = P8 ^ P9, c3 = P8 & P9;
    u64 gh = s1 ^ s2;
    u64 b0 = gh ^ s3, c4 = (s1 & s2) | (gh & s3);
    u64 ij = c1 ^ c2;
    u64 s4 = ij ^ c3, c5 = (c1 & c2) | (ij & c3);
    u64 b1 = s4 ^ c4, c6 = s4 & c4;
    u64 b2 = c5 ^ c6, b3 = c5 & c6;

    u64 Bge2 = b1 | b2 | b3;
    u64 Ble6 = ~(b3 | (b2 & b1 & b0));

    u64 a1, a2, t;
    t = ~P2 & P3; a1 = t; a2 = 0ULL;
    t = ~P3 & P4; a2 |= a1 & t; a1 |= t;
    t = ~P4 & P5; a2 |= a1 & t; a1 |= t;
    t = ~P5 & P6; a2 |= a1 & t; a1 |= t;
    t = ~P6 & P7; a2 |= a1 & t; a1 |= t;
    t = ~P7 & P8; a2 |= a1 & t; a1 |= t;
    t = ~P8 & P9; a2 |= a1 & t; a1 |= t;
    t = ~P9 & P2; a2 |= a1 & t; a1 |= t;
    u64 Aeq1 = a1 & ~a2;

    u64 sccond = (step == 0) ? ~((P4 & P6) & (P2 | P8))
                             : ~((P2 & P8) & (P4 | P6));

    return cc & ~(Bge2 & Ble6 & Aeq1 & sccond);
}

// spread 16 bits to positions 0,4,8,...,60
__device__ __forceinline__ u64 spread4(u64 x) {
    x = (x | (x << 24)) & 0x000000FF000000FFULL;
    x = (x | (x << 12)) & 0x000F000F000F000FULL;
    x = (x | (x << 6))  & 0x0303030303030303ULL;
    x = (x | (x << 3))  & 0x1111111111111111ULL;
    return x;
}

// ---------------- pack: coalesced binarize (8192 blocks x 256 threads) -------
// One float4 per lane; 4 ballots; lanes 0-3 bit-spread into the wave's 4 u64.
// Block 0 zeroes cnt[64] + flags[3*32] + done[1] = 161 ints.
__global__ __launch_bounds__(256)
void pack_kernel(const float* __restrict__ y_pred,
                 const float* __restrict__ y_true,
                 u64* __restrict__ bits /* buf0 */,
                 int* __restrict__ cnt) {
    int tid = threadIdx.x;
    if (blockIdx.x == 0 && tid < 4 * NB + 3 * NIMG + 1) cnt[tid] = 0;

    int t = blockIdx.x * 256 + tid;
    int lane = tid & 63;
    size_t p0 = (size_t)t * 4;
    const float* src;
    size_t off;
    if (p0 < (size_t)NB * HW) { src = y_pred; off = p0; }
    else                      { src = y_true; off = p0 - (size_t)NB * HW; }
    float4 a = *(const float4*)(src + off);
    unsigned nib = (unsigned)(a.x > 0.5f)
                 | ((unsigned)(a.y > 0.5f) << 1)
                 | ((unsigned)(a.z > 0.5f) << 2)
                 | ((unsigned)(a.w > 0.5f) << 3);
    u64 b0 = __ballot(nib & 1u);
    u64 b1 = __ballot(nib & 2u);
    u64 b2 = __ballot(nib & 4u);
    u64 b3 = __ballot(nib & 8u);
    if (lane < 4) {
        unsigned sh = lane * 16;
        u64 w = spread4((b0 >> sh) & 0xFFFFu)
              | (spread4((b1 >> sh) & 0xFFFFu) << 1)
              | (spread4((b2 >> sh) & 0xFFFFu) << 2)
              | (spread4((b3 >> sh) & 0xFFFFu) << 3);
        size_t wave = (size_t)t >> 6;
        bits[wave * 4 + lane] = w;
    }
}

// ---------------- cooperative: strip-thin to convergence + count + reduce ----
#define SSTRIPS 8
#define SIROWS (HH / SSTRIPS)          // 64 interior rows
#define SHALO 24
#define SDROWS (SIROWS + 2 * SHALO)    // 112 domain rows
#define CTHREADS (SDROWS * WPR)        // 896 threads, 1 word each
#define SITERS (SHALO / 2)             // 12 local iterations = 24 exact phases
#define SSTR 10
#define SLWORDS ((SDROWS + 2) * SSTR)  // 1140 words per buffer
#define MAXPASS 24                     // 576 phases >= ZS worst case (~512)

#define STRIPS 8
#define SROWS (HH / STRIPS)            // count-strip interior rows
#define SR2 (SROWS + 6)

__device__ __forceinline__ u64 ldws(const u64* M, int r, int c) {
    return (c < 0 || c >= WPR) ? 0ULL : M[r * WPR + c];
}

// radius-3 disk dilation; r in [3, 3+SROWS)
__device__ __forceinline__ u64 dil3s(const u64* M, int r, int c) {
    u64 cm = ldws(M, r, c - 1), cc = ldws(M, r, c), cp = ldws(M, r, c + 1);
    u64 h = cc
          | (cc >> 1) | (cp << 63)
          | (cc >> 2) | (cp << 62)
          | (cc >> 3) | (cp << 61)
          | (cc << 1) | (cm >> 63)
          | (cc << 2) | (cm >> 62)
          | (cc << 3) | (cm >> 61);
    u64 um = ldws(M, r - 1, c - 1) | ldws(M, r + 1, c - 1) | ldws(M, r - 2, c - 1) | ldws(M, r + 2, c - 1);
    u64 uc = ldws(M, r - 1, c    ) | ldws(M, r + 1, c    ) | ldws(M, r - 2, c    ) | ldws(M, r + 2, c    );
    u64 up = ldws(M, r - 1, c + 1) | ldws(M, r + 1, c + 1) | ldws(M, r - 2, c + 1) | ldws(M, r + 2, c + 1);
    h |= uc
       | (uc >> 1) | (up << 63)
       | (uc >> 2) | (up << 62)
       | (uc << 1) | (um >> 63)
       | (uc << 2) | (um >> 62);
    h |= ldws(M, r - 3, c) | ldws(M, r + 3, c);
    return h;
}

// Pass p: reads buf[p&1], writes buf[(p+1)&1]; writes flag slot p%3, zeroes
// slot (p+1)%3 (pre-sync, read only after NEXT pass's sync -> race-free),
// scans slot p%3 after the single grid.sync per pass. Exit is grid-uniform.
__global__ __launch_bounds__(CTHREADS, 4)
void coop_kernel(u64* __restrict__ buf0, u64* __restrict__ buf1,
                 int* __restrict__ cnt, int* __restrict__ flags /*[3][NIMG]*/,
                 int* __restrict__ done, float* __restrict__ out) {
    cg::grid_group grid = cg::this_grid();
    __shared__ u64 Mb[2][SLWORDS];          // 2 x 9120 B
    __shared__ unsigned int Cpb[2][SDROWS + 2];
    __shared__ int s_any[3];
    __shared__ int s_acc[4];
    __shared__ int s_lastf;

    int bx = blockIdx.x;
    int img = bx >> 3;
    int s = bx & 7;
    int tid = threadIdx.x;                  // 0..895
    int lane = tid & 63;
    int r = tid >> 3;                       // domain row 0..111
    int c = tid & 7;
    int gr = s * SIROWS - SHALO + r;
    bool grin = (gr >= 0 && gr < HH);
    int gw = gr * WPR + c;
    int base = (r + 1) * SSTR + (c + 1);

    int fin = 0;
    for (int p = 0; p < MAXPASS; ++p) {
        const u64* src = ((p & 1) ? buf1 : buf0) + (size_t)img * NWORDS;
        u64* dst = ((p & 1) ? buf0 : buf1) + (size_t)img * NWORDS;
        if (s == 0 && tid == 0) flags[((p + 1) % 3) * NIMG + img] = 0;

        for (int i = tid; i < SLWORDS; i += CTHREADS) { Mb[0][i] = 0; Mb[1][i] = 0; }
        if (tid < SDROWS + 2) {
            Cpb[0][tid] = (tid >= 1 && tid <= SDROWS) ? 0x1FEu : 0u;
            Cpb[1][tid] = 0u;
        }
        if (tid < 3) s_any[tid] = 0;
        __syncthreads();
        Mb[0][base] = grin ? src[gw] : 0ULL;

        unsigned dl = 0x1FEu;
        bool prevchg = true;
        int it = 0;
        bool ldone = false;
        for (;;) {
            for (int step = 0; step < 2; ++step) {
                __syncthreads();            // orders prior phase's writes
                if (step == 0 && it > 0) {
                    if (s_any[(it + 2) % 3] == 0) { ldone = true; break; }
                }
                const u64* Ms = Mb[step];
                u64* Md = Mb[step ^ 1];
                const unsigned* CpS = Cpb[step];
                unsigned* CpD = Cpb[step ^ 1];

                unsigned need = ((CpS[r] | CpS[r + 1] | CpS[r + 2]) >> c) & 7u;
                bool chg = false;
                if (need) {
                    u64 cc = Ms[base];
                    u64 nv = cc;
                    if (cc) {               // zero words can never gain pixels
                        u64 nm = Ms[base - SSTR - 1], nc = Ms[base - SSTR], np = Ms[base - SSTR + 1];
                        u64 cm = Ms[base - 1],                              cp = Ms[base + 1];
                        u64 sm = Ms[base + SSTR - 1], sc = Ms[base + SSTR], sp = Ms[base + SSTR + 1];
                        u64 P2 = nc;
                        u64 P3 = (nc >> 1) | (np << 63);
                        u64 P4 = (cc >> 1) | (cp << 63);
                        u64 P5 = (sc >> 1) | (sp << 63);
                        u64 P6 = sc;
                        u64 P7 = (sc << 1) | (sm >> 63);
                        u64 P8 = (cc << 1) | (cm >> 63);
                        u64 P9 = (nc << 1) | (nm >> 63);
                        nv = zs_core(cc, P2, P3, P4, P5, P6, P7, P8, P9, step);
                        chg = (nv != cc);
                    }
                    // need==0 => prevchg==false: store-skip safe
                    if (chg | prevchg) Md[base] = nv;
                }
                prevchg = chg;
                u64 bal = __ballot(chg);
                if (bal && lane == 0) s_any[it % 3] = 1;   // benign same-value race
                if ((lane & 7) == 0) {
                    unsigned byte = ((unsigned)(bal >> lane) & 0xFFu) << 1;
                    CpD[r + 1] = byte | dl;
                    dl = byte;
                }
                if (step == 1 && tid == 0) s_any[(it + 1) % 3] = 0;
            }
            if (ldone) break;
            if (++it >= SITERS) break;
        }
        __syncthreads();                    // last iteration's s_any visible
        int lastAny = ldone ? 0 : s_any[(SITERS - 1) % 3];

        if (r >= SHALO && r < SHALO + SIROWS) dst[gw] = Mb[0][base];
        if (lastAny && tid == 0) flags[(p % 3) * NIMG + img] = 1;

        grid.sync();                        // publishes dst + flags grid-wide

        int any = 0;
        const int* f = flags + (p % 3) * NIMG;
        for (int i = 0; i < NIMG; ++i) any |= f[i];
        fin = (p + 1) & 1;
        if (!any) break;                    // uniform: same flags read by all
    }

    // ---- count phase: blocks 0..127 (one image-pair strip each) ----
    if (bx >= NB * STRIPS) return;
    {
        u64* Pl = Mb[0];                    // 560 of 1140 words used
        u64* Gl = Mb[1];
        int b = bx >> 3;
        int cs = bx & 7;
        int r0 = cs * SROWS - 3;
        const u64* fb = fin ? buf1 : buf0;
        const u64* sp = fb + (size_t)b * NWORDS;
        const u64* sg = fb + (size_t)(NB + b) * NWORDS;
        for (int i = tid; i < SR2 * WPR; i += CTHREADS) {
            int grr = r0 + (i >> 3);
            bool in = (grr >= 0 && grr < HH);
            int gi = grr * WPR + (i & 7);
            Pl[i] = in ? sp[gi] : 0ULL;
            Gl[i] = in ? sg[gi] : 0ULL;
        }
        if (tid < 4) s_acc[tid] = 0;
        __syncthreads();

        int cp = 0, cg2 = 0, tp = 0, fnh = 0;
        if (tid < SROWS * WPR) {            // 512 interior words
            int rr = (tid >> 3) + 3, c2 = tid & 7;
            u64 pw = Pl[rr * WPR + c2], gw2 = Gl[rr * WPR + c2];
            cp  = __popcll(pw);
            cg2 = __popcll(gw2);
            tp  = __popcll(pw & dil3s(Gl, rr, c2));
            fnh = __popcll(gw2 & dil3s(Pl, rr, c2));
        }
        #pragma unroll
        for (int o = 32; o > 0; o >>= 1) {
            cp  += __shfl_down(cp, o);
            cg2 += __shfl_down(cg2, o);
            tp  += __shfl_down(tp, o);
            fnh += __shfl_down(fnh, o);
        }
        if (lane == 0) {
            atomicAdd(&s_acc[0], cp);
            atomicAdd(&s_acc[1], cg2);
            atomicAdd(&s_acc[2], tp);
            atomicAdd(&s_acc[3], fnh);
        }
        __syncthreads();
        if (tid < 4) atomicAdd(&cnt[b * 4 + tid], s_acc[tid]);
        __syncthreads();
        if (tid == 0) {
            __threadfence();                // release this block's counts
            s_lastf = (atomicAdd(done, 1) == NB * STRIPS - 1);
        }
        __syncthreads();
        if (!s_lastf) return;
        __threadfence();                    // acquire all counts

        if (tid < 3) {
            float sacc = 0.0f;
            for (int i = 0; i < NB; ++i) {
                float c0 = (float)atomicAdd(&cnt[i * 4 + 0], 0);
                float c1 = (float)atomicAdd(&cnt[i * 4 + 1], 0);
                float TP = (float)atomicAdd(&cnt[i * 4 + 2], 0);
                float c3 = (float)atomicAdd(&cnt[i * 4 + 3], 0);
                float FP = c0 - TP;
                float FN = c1 - c3;
                float v = (tid == 0) ? TP / (TP + FP + 1e-12f)
                        : (tid == 1) ? TP / (TP + FN + 1e-12f)
                                     : TP / (TP + FP + FN + 1e-12f);
                sacc += v;
            }
            out[tid] = sacc * (1.0f / NB);
        }
    }
}

// ---------------- fallback path (used only if cooperative launch fails) ------
__global__ __launch_bounds__(CTHREADS)
void strip_kernel(const u64* __restrict__ src, u64* __restrict__ dst,
                  int* __restrict__ flags, int rec) {
    __shared__ u64 Mb[2][SLWORDS];
    __shared__ unsigned int Cpb[2][SDROWS + 2];
    __shared__ int s_any[3];

    int bx = blockIdx.x;
    int img = bx >> 3;
    int s = bx & 7;
    int tid = threadIdx.x;
    int lane = tid & 63;
    int r = tid >> 3;
    int c = tid & 7;
    int gr = s * SIROWS - SHALO + r;

    for (int i = tid; i < SLWORDS; i += CTHREADS) { Mb[0][i] = 0; Mb[1][i] = 0; }
    if (tid < SDROWS + 2) {
        Cpb[0][tid] = (tid >= 1 && tid <= SDROWS) ? 0x1FEu : 0u;
        Cpb[1][tid] = 0u;
    }
    if (tid < 3) s_any[tid] = 0;
    __syncthreads();

    const u64* gsrc = src + (size_t)img * NWORDS;
    u64 v = (gr >= 0 && gr < HH) ? gsrc[gr * WPR + c] : 0ULL;
    int base = (r + 1) * SSTR + (c + 1);
    Mb[0][base] = v;

    unsigned dl = 0x1FEu;
    bool prevchg = true;
    int it = 0;
    bool done = false;
    for (;;) {
        for (int step = 0; step < 2; ++step) {
            __syncthreads();
            if (step == 0 && it > 0) {
                if (s_any[(it + 2) % 3] == 0) { done = true; break; }
            }
            const u64* Ms = Mb[step];
            u64* Md = Mb[step ^ 1];
            const unsigned* CpS = Cpb[step];
            unsigned* CpD = Cpb[step ^ 1];
            unsigned need = ((CpS[r] | CpS[r + 1] | CpS[r + 2]) >> c) & 7u;
            bool chg = false;
            if (need) {
                u64 cc = Ms[base];
                u64 nv = cc;
                if (cc) {
                    u64 nm = Ms[base - SSTR - 1], nc = Ms[base - SSTR], np = Ms[base - SSTR + 1];
                    u64 cm = Ms[base - 1],                              cp = Ms[base + 1];
                    u64 sm = Ms[base + SSTR - 1], sc = Ms[base + SSTR], sp = Ms[base + SSTR + 1];
                    u64 P2 = nc;
                    u64 P3 = (nc >> 1) | (np << 63);
                    u64 P4 = (cc >> 1) | (cp << 63);
                    u64 P5 = (sc >> 1) | (sp << 63);
                    u64 P6 = sc;
                    u64 P7 = (sc << 1) | (sm >> 63);
                    u64 P8 = (cc << 1) | (cm >> 63);
                    u64 P9 = (nc << 1) | (nm >> 63);
                    nv = zs_core(cc, P2, P3, P4, P5, P6, P7, P8, P9, step);
                    chg = (nv != cc);
                }
                if (chg | prevchg) Md[base] = nv;
            }
            prevchg = chg;
            u64 bal = __ballot(chg);
            if (bal && lane == 0) s_any[it % 3] = 1;
            if ((lane & 7) == 0) {
                unsigned byte = ((unsigned)(bal >> lane) & 0xFFu) << 1;
                CpD[r + 1] = byte | dl;
                dl = byte;
            }
            if (step == 1 && tid == 0) s_any[(it + 1) % 3] = 0;
        }
        if (done) break;
        if (++it >= SITERS) break;
    }
    __syncthreads();
    int lastAny = done ? 0 : s_any[(SITERS - 1) % 3];
    if (r >= SHALO && r < SHALO + SIROWS) {
        dst[(size_t)img * NWORDS + gr * WPR + c] = Mb[0][base];
    }
    if (rec && lastAny && tid == 0) flags[img] = 1;
}

#define LSTR 10
#define LROWS (HH + 2)
#define LWORDS (LROWS * LSTR)
#define NTHREADS 1024

__global__ __launch_bounds__(NTHREADS, 4)
void skel_kernel(u64* __restrict__ bits, const int* __restrict__ flags) {
    __shared__ u64 Mb[2][LWORDS];
    __shared__ unsigned int Cpb[2][130];
    __shared__ int s_any[3];

    int bx = blockIdx.x;
    if (flags[bx] == 0) return;

    int tid = threadIdx.x;
    int lane = tid & 63;
    int c = tid & 7;
    int rb = tid >> 3;

    u64* gm = bits + (size_t)bx * NWORDS;

    if (tid < LROWS) {
        int i = tid;
        if (i == 0 || i == LROWS - 1) {
            #pragma unroll
            for (int j = 0; j < LSTR; ++j) { Mb[0][i * LSTR + j] = 0; Mb[1][i * LSTR + j] = 0; }
        } else {
            Mb[0][i * LSTR + 0] = 0; Mb[0][i * LSTR + 9] = 0;
            Mb[1][i * LSTR + 0] = 0; Mb[1][i * LSTR + 9] = 0;
        }
    }
    {
        const ulonglong2* s2 = (const ulonglong2*)gm;
        #pragma unroll
        for (int k = 0; k < 2; ++k) {
            int i = k * NTHREADS + tid;
            ulonglong2 v = s2[i];
            int wi = i * 2;
            int r = wi >> 3, c2 = wi & 7;
            int li = (r + 1) * LSTR + c2 + 1;
            Mb[0][li] = v.x;
            Mb[0][li + 1] = v.y;
        }
    }
    if (tid < 130) {
        Cpb[0][tid] = (tid >= 1 && tid <= 128) ? 0x1FEu : 0u;
        Cpb[1][tid] = 0u;
    }
    if (tid < 3) s_any[tid] = 0;

    unsigned dl = 0x1FEu;
    bool prevchg = true;
    int base = (rb * 4 + 1) * LSTR + (c + 1);

    int it = 0;
    bool done = false;
    for (;;) {
        for (int step = 0; step < 2; ++step) {
            __syncthreads();
            if (step == 0 && it > 0) {
                if (s_any[(it + 2) % 3] == 0) { done = true; break; }
            }
            const u64* Ms = Mb[step];
            u64* Md = Mb[step ^ 1];
            const unsigned* CpS = Cpb[step];
            unsigned* CpD = Cpb[step ^ 1];
            unsigned need = ((CpS[rb] | CpS[rb + 1] | CpS[rb + 2]) >> c) & 7u;
            bool chg = false;
            if (need) {
                u64 Ca, Ea, Wa, Cb, Eb, Wb, Cc, Ec, Wc;
                {   int a = base - LSTR;
                    u64 x = Ms[a], mm = Ms[a - 1], pp = Ms[a + 1];
                    Ca = x; Ea = (x >> 1) | (pp << 63); Wa = (x << 1) | (mm >> 63); }
                {   int a = base;
                    u64 x = Ms[a], mm = Ms[a - 1], pp = Ms[a + 1];
                    Cb = x; Eb = (x >> 1) | (pp << 63); Wb = (x << 1) | (mm >> 63); }
                u64 nv0 = 0, nv1 = 0, nv2 = 0, nv3 = 0;
                {   int a = base + LSTR;
                    u64 x = Ms[a], mm = Ms[a - 1], pp = Ms[a + 1];
                    Cc = x; Ec = (x >> 1) | (pp << 63); Wc = (x << 1) | (mm >> 63);
                    if (Cb) nv0 = zs_core(Cb, Ca, Ea, Eb, Ec, Cc, Wc, Wb, Wa, step);
                    chg |= (nv0 != Cb);
                    Ca = Cb; Ea = Eb; Wa = Wb; Cb = Cc; Eb = Ec; Wb = Wc; }
                {   int a = base + 2 * LSTR;
                    u64 x = Ms[a], mm = Ms[a - 1], pp = Ms[a + 1];
                    Cc = x; Ec = (x >> 1) | (pp << 63); Wc = (x << 1) | (mm >> 63);
                    if (Cb) nv1 = zs_core(Cb, Ca, Ea, Eb, Ec, Cc, Wc, Wb, Wa, step);
                    chg |= (nv1 != Cb);
                    Ca = Cb; Ea = Eb; Wa = Wb; Cb = Cc; Eb = Ec; Wb = Wc; }
                {   int a = base + 3 * LSTR;
                    u64 x = Ms[a], mm = Ms[a - 1], pp = Ms[a + 1];
                    Cc = x; Ec = (x >> 1) | (pp << 63); Wc = (x << 1) | (mm >> 63);
                    if (Cb) nv2 = zs_core(Cb, Ca, Ea, Eb, Ec, Cc, Wc, Wb, Wa, step);
                    chg |= (nv2 != Cb);
                    Ca = Cb; Ea = Eb; Wa = Wb; Cb = Cc; Eb = Ec; Wb = Wc; }
                {   int a = base + 4 * LSTR;
                    u64 x = Ms[a], mm = Ms[a - 1], pp = Ms[a + 1];
                    Cc = x; Ec = (x >> 1) | (pp << 63); Wc = (x << 1) | (mm >> 63);
                    if (Cb) nv3 = zs_core(Cb, Ca, Ea, Eb, Ec, Cc, Wc, Wb, Wa, step);
                    chg |= (nv3 != Cb); }
                if (chg | prevchg) {
                    Md[base] = nv0;
                    Md[base + LSTR] = nv1;
                    Md[base + 2 * LSTR] = nv2;
                    Md[base + 3 * LSTR] = nv3;
                }
            }
            prevchg = chg;
            u64 bal = __ballot(chg);
            if (bal && lane == 0) s_any[it % 3] = 1;
            if ((lane & 7) == 0) {
                unsigned byte = ((unsigned)(bal >> lane) & 0xFFu) << 1;
                CpD[rb + 1] = byte | dl;
                dl = byte;
            }
            if (step == 1 && tid == 0) s_any[(it + 1) % 3] = 0;
        }
        if (done || it >= 1024) break;
        ++it;
    }

    {
        ulonglong2* d2 = (ulonglong2*)gm;
        #pragma unroll
        for (int k = 0; k < 2; ++k) {
            int i = k * NTHREADS + tid;
            int wi = i * 2;
            int r = wi >> 3, c2 = wi & 7;
            int li = (r + 1) * LSTR + c2 + 1;
            ulonglong2 v;
            v.x = Mb[0][li];
            v.y = Mb[0][li + 1];
            d2[i] = v;
        }
    }
}

__global__ __launch_bounds__(256)
void count_kernel(const u64* __restrict__ skel, int* __restrict__ cnt,
                  int* __restrict__ done, float* __restrict__ out) {
    __shared__ u64 P[SR2 * WPR];
    __shared__ u64 G[SR2 * WPR];
    __shared__ int acc[4];
    __shared__ int s_last;

    int b = blockIdx.x / STRIPS;
    int s = blockIdx.x % STRIPS;
    int tid = threadIdx.x;
    int r0 = s * SROWS - 3;

    const u64* sp = skel + (size_t)b * NWORDS;
    const u64* sg = skel + (size_t)(NB + b) * NWORDS;
    for (int i = tid; i < SR2 * WPR; i += 256) {
        int gr = r0 + (i >> 3);
        bool in = (gr >= 0 && gr < HH);
        int gi = gr * WPR + (i & 7);
        P[i] = in ? sp[gi] : 0ULL;
        G[i] = in ? sg[gi] : 0ULL;
    }
    if (tid < 4) acc[tid] = 0;
    __syncthreads();

    int cp = 0, cg = 0, tp = 0, fnh = 0;
    #pragma unroll
    for (int k = 0; k < 2; ++k) {
        int w = k * 256 + tid;
        int r = (w >> 3) + 3, c = w & 7;
        u64 pw = P[r * WPR + c], gw = G[r * WPR + c];
        cp  += __popcll(pw);
        cg  += __popcll(gw);
        tp  += __popcll(pw & dil3s(G, r, c));
        fnh += __popcll(gw & dil3s(P, r, c));
    }
    #pragma unroll
    for (int o = 32; o > 0; o >>= 1) {
        cp  += __shfl_down(cp, o);
        cg  += __shfl_down(cg, o);
        tp  += __shfl_down(tp, o);
        fnh += __shfl_down(fnh, o);
    }
    if ((tid & 63) == 0) {
        atomicAdd(&acc[0], cp);
        atomicAdd(&acc[1], cg);
        atomicAdd(&acc[2], tp);
        atomicAdd(&acc[3], fnh);
    }
    __syncthreads();
    if (tid < 4) atomicAdd(&cnt[b * 4 + tid], acc[tid]);
    __syncthreads();
    if (tid == 0) {
        __threadfence();
        s_last = (atomicAdd(done, 1) == NB * STRIPS - 1);
    }
    __syncthreads();
    if (!s_last) return;
    __threadfence();

    if (tid < 3) {
        float sacc = 0.0f;
        for (int i = 0; i < NB; ++i) {
            float c0 = (float)atomicAdd(&cnt[i * 4 + 0], 0);
            float c1 = (float)atomicAdd(&cnt[i * 4 + 1], 0);
            float TP = (float)atomicAdd(&cnt[i * 4 + 2], 0);
            float c3 = (float)atomicAdd(&cnt[i * 4 + 3], 0);
            float FP = c0 - TP;
            float FN = c1 - c3;
            float v = (tid == 0) ? TP / (TP + FP + 1e-12f)
                    : (tid == 1) ? TP / (TP + FN + 1e-12f)
                                 : TP / (TP + FP + FN + 1e-12f);
            sacc += v;
        }
        out[tid] = sacc * (1.0f / NB);
    }
}

extern "C" void kernel_launch(void* const* d_in, const int* in_sizes, int n_in,
                              void* d_out, int out_size, void* d_ws, size_t ws_size,
                              hipStream_t stream) {
    (void)in_sizes; (void)n_in; (void)out_size; (void)ws_size;
    const float* y_pred = (const float*)d_in[0];
    const float* y_true = (const float*)d_in[1];
    float* out = (float*)d_out;

    u64* buf0 = (u64*)d_ws;                               // 1 MB
    u64* buf1 = buf0 + (size_t)NIMG * NWORDS;             // 1 MB
    int* cnt = (int*)(buf1 + (size_t)NIMG * NWORDS);      // 64 ints
    int* flags = cnt + 4 * NB;                            // 96 ints (3 slots x 32)
    int* done = flags + 3 * NIMG;                         // 1 int

    hipLaunchKernelGGL(pack_kernel, dim3(2 * NB * HW / 4 / 256), dim3(256), 0, stream,
                       y_pred, y_true, buf0, cnt);

    {
        u64* a0 = buf0; u64* a1 = buf1;
        int* ac = cnt; int* af = flags; int* ad = done;
        float* ao = out;
        void* args[] = {&a0, &a1, &ac, &af, &ad, &ao};
        hipError_t e = hipLaunchCooperativeKernel((const void*)coop_kernel,
                                                  dim3(NIMG * SSTRIPS), dim3(CTHREADS),
                                                  args, 0, stream);
        if (e != hipSuccess) {
            // fallback: proven 4-kernel path (flags slot 0 doubles as per-image flag)
            hipLaunchKernelGGL(strip_kernel, dim3(NIMG * SSTRIPS), dim3(CTHREADS), 0, stream,
                               buf0, buf1, flags, 0);
            hipLaunchKernelGGL(strip_kernel, dim3(NIMG * SSTRIPS), dim3(CTHREADS), 0, stream,
                               buf1, buf0, flags, 1);
            hipLaunchKernelGGL(skel_kernel, dim3(NIMG), dim3(NTHREADS), 0, stream,
                               buf0, flags);
            hipLaunchKernelGGL(count_kernel, dim3(NB * STRIPS), dim3(256), 0, stream,
                               buf0, cnt, done, out);
        }
    }
}

// Round 9
// 114.507 us; speedup vs baseline: 1.2885x; 1.2885x over previous
//
#include <hip/hip_runtime.h>
#include <stdint.h>

#define HH 512
#define WW 512
#define HW (HH * WW)          // 262144 pixels per image
#define WPR 8                 // u64 words per row (global layout)
#define NWORDS (HH * WPR)     // 4096 words per image
#define NB 16                 // batch
#define NIMG (2 * NB)         // 32 masks

typedef unsigned long long u64;

// Zhang-Suen sub-step core on prebuilt neighbor views (bit k = pixel col k).
__device__ __forceinline__ u64 zs_core(u64 cc, u64 P2, u64 P3, u64 P4, u64 P5,
                                       u64 P6, u64 P7, u64 P8, u64 P9, int step) {
    u64 ab = P2 ^ P3;
    u64 s1 = ab ^ P4, c1 = (P2 & P3) | (ab & P4);
    u64 de = P5 ^ P6;
    u64 s2 = de ^ P7, c2 = (P5 & P6) | (de & P7);
    u64 s3 = P8 ^ P9, c3 = P8 & P9;
    u64 gh = s1 ^ s2;
    u64 b0 = gh ^ s3, c4 = (s1 & s2) | (gh & s3);
    u64 ij = c1 ^ c2;
    u64 s4 = ij ^ c3, c5 = (c1 & c2) | (ij & c3);
    u64 b1 = s4 ^ c4, c6 = s4 & c4;
    u64 b2 = c5 ^ c6, b3 = c5 & c6;

    u64 Bge2 = b1 | b2 | b3;
    u64 Ble6 = ~(b3 | (b2 & b1 & b0));

    u64 a1, a2, t;
    t = ~P2 & P3; a1 = t; a2 = 0ULL;
    t = ~P3 & P4; a2 |= a1 & t; a1 |= t;
    t = ~P4 & P5; a2 |= a1 & t; a1 |= t;
    t = ~P5 & P6; a2 |= a1 & t; a1 |= t;
    t = ~P6 & P7; a2 |= a1 & t; a1 |= t;
    t = ~P7 & P8; a2 |= a1 & t; a1 |= t;
    t = ~P8 & P9; a2 |= a1 & t; a1 |= t;
    t = ~P9 & P2; a2 |= a1 & t; a1 |= t;
    u64 Aeq1 = a1 & ~a2;

    u64 sccond = (step == 0) ? ~((P4 & P6) & (P2 | P8))
                             : ~((P2 & P8) & (P4 | P6));

    return cc & ~(Bge2 & Ble6 & Aeq1 & sccond);
}

// spread 16 bits to positions 0,4,8,...,60
__device__ __forceinline__ u64 spread4(u64 x) {
    x = (x | (x << 24)) & 0x000000FF000000FFULL;
    x = (x | (x << 12)) & 0x000F000F000F000FULL;
    x = (x | (x << 6))  & 0x0303030303030303ULL;
    x = (x | (x << 3))  & 0x1111111111111111ULL;
    return x;
}

// ---------------- pack: coalesced binarize (8192 blocks x 256 threads) -------
// One float4 per lane; 4 ballots; lanes 0-3 bit-spread into the wave's 4 u64.
// Block 0 zeroes cnt[64] + flags[32] + done[1] = 97 ints.
__global__ __launch_bounds__(256)
void pack_kernel(const float* __restrict__ y_pred,
                 const float* __restrict__ y_true,
                 u64* __restrict__ bits /* buf0 */,
                 int* __restrict__ cnt) {
    int tid = threadIdx.x;
    if (blockIdx.x == 0 && tid < 4 * NB + NIMG + 1) cnt[tid] = 0;

    int t = blockIdx.x * 256 + tid;
    int lane = tid & 63;
    size_t p0 = (size_t)t * 4;
    const float* src;
    size_t off;
    if (p0 < (size_t)NB * HW) { src = y_pred; off = p0; }
    else                      { src = y_true; off = p0 - (size_t)NB * HW; }
    float4 a = *(const float4*)(src + off);
    unsigned nib = (unsigned)(a.x > 0.5f)
                 | ((unsigned)(a.y > 0.5f) << 1)
                 | ((unsigned)(a.z > 0.5f) << 2)
                 | ((unsigned)(a.w > 0.5f) << 3);
    u64 b0 = __ballot(nib & 1u);
    u64 b1 = __ballot(nib & 2u);
    u64 b2 = __ballot(nib & 4u);
    u64 b3 = __ballot(nib & 8u);
    if (lane < 4) {
        unsigned sh = lane * 16;
        u64 w = spread4((b0 >> sh) & 0xFFFFu)
              | (spread4((b1 >> sh) & 0xFFFFu) << 1)
              | (spread4((b2 >> sh) & 0xFFFFu) << 2)
              | (spread4((b3 >> sh) & 0xFFFFu) << 3);
        size_t wave = (size_t)t >> 6;
        bits[wave * 4 + lane] = w;
    }
}

// ---------------- strip thinning: 512 blocks (2/CU), regular launches --------
// 16 strips/image of 32 interior rows + 16-row halo each side; 8 local ZS
// iterations = 16 exact phases per pass (validity shrinks 1 row/phase, halo 16
// covers it; interior rows at distance >=16 from cut edges stay exact all pass
// and NEVER see halo garbage). rec=1: record per-image non-convergence from
// INTERIOR-row changes only in the final executed local iteration — exactly
// sound: any true global change in phases 15-16 of the pass lands in some
// strip's interior and is reproduced there.
#define SSTRIPS 16
#define SIROWS (HH / SSTRIPS)          // 32 interior rows
#define SHALO 16
#define SDROWS (SIROWS + 2 * SHALO)    // 64 domain rows
#define STHREADS (SDROWS * WPR)        // 512 threads, 1 word each
#define SITERS (SHALO / 2)             // 8 local iterations = 16 exact phases
#define SSTR 10
#define SLWORDS ((SDROWS + 2) * SSTR)  // 660 words per buffer

__global__ __launch_bounds__(STHREADS)
void strip_kernel(const u64* __restrict__ src, u64* __restrict__ dst,
                  int* __restrict__ flags, int rec) {
    __shared__ u64 Mb[2][SLWORDS];     // 2 x 5280 B
    __shared__ unsigned int Cpb[2][SDROWS + 2];
    __shared__ int s_any[3];
    __shared__ int s_anyI[3];

    int bx = blockIdx.x;
    int img = bx >> 4;
    int s = bx & 15;
    int tid = threadIdx.x;             // 0..511
    int lane = tid & 63;
    int r = tid >> 3;                  // domain row 0..63
    int c = tid & 7;
    int gr = s * SIROWS - SHALO + r;   // global row of this thread's word
    bool interior = (r >= SHALO && r < SHALO + SIROWS);

    for (int i = tid; i < SLWORDS; i += STHREADS) { Mb[0][i] = 0; Mb[1][i] = 0; }
    if (tid < SDROWS + 2) {
        Cpb[0][tid] = (tid >= 1 && tid <= SDROWS) ? 0x1FEu : 0u;
        Cpb[1][tid] = 0u;              // guards stay 0 forever
    }
    if (tid < 3) { s_any[tid] = 0; s_anyI[tid] = 0; }
    __syncthreads();

    const u64* gsrc = src + (size_t)img * NWORDS;
    u64 v = (gr >= 0 && gr < HH) ? gsrc[gr * WPR + c] : 0ULL;
    int base = (r + 1) * SSTR + (c + 1);
    Mb[0][base] = v;

    unsigned dl = 0x1FEu;              // row-owner's "last sub-step" byte
    bool prevchg = true;
    int it = 0;
    bool done = false;
    for (;;) {
        for (int step = 0; step < 2; ++step) {
            __syncthreads();           // orders prior phase's writes
            if (step == 0 && it > 0) {
                if (s_any[(it + 2) % 3] == 0) { done = true; break; }
            }
            const u64* Ms = Mb[step];
            u64* Md = Mb[step ^ 1];
            const unsigned* CpS = Cpb[step];
            unsigned* CpD = Cpb[step ^ 1];

            unsigned need = ((CpS[r] | CpS[r + 1] | CpS[r + 2]) >> c) & 7u;
            bool chg = false;
            if (need) {
                u64 cc = Ms[base];
                u64 nv = cc;
                if (cc) {              // zero words can never gain pixels
                    u64 nm = Ms[base - SSTR - 1], nc = Ms[base - SSTR], np = Ms[base - SSTR + 1];
                    u64 cm = Ms[base - 1],                              cp = Ms[base + 1];
                    u64 sm = Ms[base + SSTR - 1], sc = Ms[base + SSTR], sp = Ms[base + SSTR + 1];
                    u64 P2 = nc;
                    u64 P3 = (nc >> 1) | (np << 63);
                    u64 P4 = (cc >> 1) | (cp << 63);
                    u64 P5 = (sc >> 1) | (sp << 63);
                    u64 P6 = sc;
                    u64 P7 = (sc << 1) | (sm >> 63);
                    u64 P8 = (cc << 1) | (cm >> 63);
                    u64 P9 = (nc << 1) | (nm >> 63);
                    nv = zs_core(cc, P2, P3, P4, P5, P6, P7, P8, P9, step);
                    chg = (nv != cc);
                }
                // need==0 => prevchg==false: store-skip safe
                if (chg | prevchg) Md[base] = nv;
            }
            prevchg = chg;
            u64 bal = __ballot(chg);   // wave = 8 rows x 8 cols (domain-wide)
            if (bal && lane == 0) s_any[it % 3] = 1;       // benign same-value race
            u64 balI = __ballot(chg && interior);          // interior-only
            if (balI && lane == 0) s_anyI[it % 3] = 1;
            if ((lane & 7) == 0) {     // one owner lane per row
                unsigned byte = ((unsigned)(bal >> lane) & 0xFFu) << 1;
                CpD[r + 1] = byte | dl;
                dl = byte;
            }
            if (step == 1 && tid == 0) { s_any[(it + 1) % 3] = 0; s_anyI[(it + 1) % 3] = 0; }
        }
        if (done) break;
        if (++it >= SITERS) break;
    }
    __syncthreads();                   // last iteration's s_anyI visible
    int lastAny = done ? 0 : s_anyI[(SITERS - 1) % 3];

    // store interior rows (phase count even at both exits -> state in Mb[0])
    if (interior) {
        dst[(size_t)img * NWORDS + gr * WPR + c] = Mb[0][base];
    }
    if (rec && lastAny && tid == 0) flags[img] = 1;        // same-value races benign
}

// ---------------- final skeletonize: fallback, skips converged images --------
#define LSTR 10
#define LROWS (HH + 2)
#define LWORDS (LROWS * LSTR)
#define NTHREADS 1024

__global__ __launch_bounds__(NTHREADS, 4)
void skel_kernel(u64* __restrict__ bits, const int* __restrict__ flags) {
    __shared__ u64 Mb[2][LWORDS];
    __shared__ unsigned int Cpb[2][130];
    __shared__ int s_any[3];

    int bx = blockIdx.x;
    if (flags[bx] == 0) return;        // strips already converged this image

    int tid = threadIdx.x;
    int lane = tid & 63;
    int c = tid & 7;
    int rb = tid >> 3;

    u64* gm = bits + (size_t)bx * NWORDS;

    if (tid < LROWS) {
        int i = tid;
        if (i == 0 || i == LROWS - 1) {
            #pragma unroll
            for (int j = 0; j < LSTR; ++j) { Mb[0][i * LSTR + j] = 0; Mb[1][i * LSTR + j] = 0; }
        } else {
            Mb[0][i * LSTR + 0] = 0; Mb[0][i * LSTR + 9] = 0;
            Mb[1][i * LSTR + 0] = 0; Mb[1][i * LSTR + 9] = 0;
        }
    }
    {
        const ulonglong2* s2 = (const ulonglong2*)gm;
        #pragma unroll
        for (int k = 0; k < 2; ++k) {
            int i = k * NTHREADS + tid;
            ulonglong2 v = s2[i];
            int wi = i * 2;
            int r = wi >> 3, c2 = wi & 7;
            int li = (r + 1) * LSTR + c2 + 1;
            Mb[0][li] = v.x;
            Mb[0][li + 1] = v.y;
        }
    }
    if (tid < 130) {
        Cpb[0][tid] = (tid >= 1 && tid <= 128) ? 0x1FEu : 0u;
        Cpb[1][tid] = 0u;
    }
    if (tid < 3) s_any[tid] = 0;

    unsigned dl = 0x1FEu;
    bool prevchg = true;
    int base = (rb * 4 + 1) * LSTR + (c + 1);

    int it = 0;
    bool done = false;
    for (;;) {
        for (int step = 0; step < 2; ++step) {
            __syncthreads();
            if (step == 0 && it > 0) {
                if (s_any[(it + 2) % 3] == 0) { done = true; break; }
            }
            const u64* Ms = Mb[step];
            u64* Md = Mb[step ^ 1];
            const unsigned* CpS = Cpb[step];
            unsigned* CpD = Cpb[step ^ 1];
            unsigned need = ((CpS[rb] | CpS[rb + 1] | CpS[rb + 2]) >> c) & 7u;
            bool chg = false;
            if (need) {
                u64 Ca, Ea, Wa, Cb, Eb, Wb, Cc, Ec, Wc;
                {   int a = base - LSTR;
                    u64 x = Ms[a], mm = Ms[a - 1], pp = Ms[a + 1];
                    Ca = x; Ea = (x >> 1) | (pp << 63); Wa = (x << 1) | (mm >> 63); }
                {   int a = base;
                    u64 x = Ms[a], mm = Ms[a - 1], pp = Ms[a + 1];
                    Cb = x; Eb = (x >> 1) | (pp << 63); Wb = (x << 1) | (mm >> 63); }
                u64 nv0 = 0, nv1 = 0, nv2 = 0, nv3 = 0;
                {   int a = base + LSTR;
                    u64 x = Ms[a], mm = Ms[a - 1], pp = Ms[a + 1];
                    Cc = x; Ec = (x >> 1) | (pp << 63); Wc = (x << 1) | (mm >> 63);
                    if (Cb) nv0 = zs_core(Cb, Ca, Ea, Eb, Ec, Cc, Wc, Wb, Wa, step);
                    chg |= (nv0 != Cb);
                    Ca = Cb; Ea = Eb; Wa = Wb; Cb = Cc; Eb = Ec; Wb = Wc; }
                {   int a = base + 2 * LSTR;
                    u64 x = Ms[a], mm = Ms[a - 1], pp = Ms[a + 1];
                    Cc = x; Ec = (x >> 1) | (pp << 63); Wc = (x << 1) | (mm >> 63);
                    if (Cb) nv1 = zs_core(Cb, Ca, Ea, Eb, Ec, Cc, Wc, Wb, Wa, step);
                    chg |= (nv1 != Cb);
                    Ca = Cb; Ea = Eb; Wa = Wb; Cb = Cc; Eb = Ec; Wb = Wc; }
                {   int a = base + 3 * LSTR;
                    u64 x = Ms[a], mm = Ms[a - 1], pp = Ms[a + 1];
                    Cc = x; Ec = (x >> 1) | (pp << 63); Wc = (x << 1) | (mm >> 63);
                    if (Cb) nv2 = zs_core(Cb, Ca, Ea, Eb, Ec, Cc, Wc, Wb, Wa, step);
                    chg |= (nv2 != Cb);
                    Ca = Cb; Ea = Eb; Wa = Wb; Cb = Cc; Eb = Ec; Wb = Wc; }
                {   int a = base + 4 * LSTR;
                    u64 x = Ms[a], mm = Ms[a - 1], pp = Ms[a + 1];
                    Cc = x; Ec = (x >> 1) | (pp << 63); Wc = (x << 1) | (mm >> 63);
                    if (Cb) nv3 = zs_core(Cb, Ca, Ea, Eb, Ec, Cc, Wc, Wb, Wa, step);
                    chg |= (nv3 != Cb); }
                if (chg | prevchg) {
                    Md[base] = nv0;
                    Md[base + LSTR] = nv1;
                    Md[base + 2 * LSTR] = nv2;
                    Md[base + 3 * LSTR] = nv3;
                }
            }
            prevchg = chg;
            u64 bal = __ballot(chg);
            if (bal && lane == 0) s_any[it % 3] = 1;
            if ((lane & 7) == 0) {
                unsigned byte = ((unsigned)(bal >> lane) & 0xFFu) << 1;
                CpD[rb + 1] = byte | dl;
                dl = byte;
            }
            if (step == 1 && tid == 0) s_any[(it + 1) % 3] = 0;
        }
        if (done || it >= 1024) break;
        ++it;
    }

    {
        ulonglong2* d2 = (ulonglong2*)gm;
        #pragma unroll
        for (int k = 0; k < 2; ++k) {
            int i = k * NTHREADS + tid;
            int wi = i * 2;
            int r = wi >> 3, c2 = wi & 7;
            int li = (r + 1) * LSTR + c2 + 1;
            ulonglong2 v;
            v.x = Mb[0][li];
            v.y = Mb[0][li + 1];
            d2[i] = v;
        }
    }
}

// ---------------- count (+ fused final reduce): 8 strips/image, 128 blocks ---
#define STRIPS 8
#define SROWS (HH / STRIPS)
#define SR2 (SROWS + 6)

__device__ __forceinline__ u64 ldws(const u64* M, int r, int c) {
    return (c < 0 || c >= WPR) ? 0ULL : M[r * WPR + c];
}

__device__ __forceinline__ u64 dil3s(const u64* M, int r, int c) {
    u64 cm = ldws(M, r, c - 1), cc = ldws(M, r, c), cp = ldws(M, r, c + 1);
    u64 h = cc
          | (cc >> 1) | (cp << 63)
          | (cc >> 2) | (cp << 62)
          | (cc >> 3) | (cp << 61)
          | (cc << 1) | (cm >> 63)
          | (cc << 2) | (cm >> 62)
          | (cc << 3) | (cm >> 61);
    u64 um = ldws(M, r - 1, c - 1) | ldws(M, r + 1, c - 1) | ldws(M, r - 2, c - 1) | ldws(M, r + 2, c - 1);
    u64 uc = ldws(M, r - 1, c    ) | ldws(M, r + 1, c    ) | ldws(M, r - 2, c    ) | ldws(M, r + 2, c    );
    u64 up = ldws(M, r - 1, c + 1) | ldws(M, r + 1, c + 1) | ldws(M, r - 2, c + 1) | ldws(M, r + 2, c + 1);
    h |= uc
       | (uc >> 1) | (up << 63)
       | (uc >> 2) | (up << 62)
       | (uc << 1) | (um >> 63)
       | (uc << 2) | (um >> 62);
    h |= ldws(M, r - 3, c) | ldws(M, r + 3, c);
    return h;
}

__global__ __launch_bounds__(256)
void count_kernel(const u64* __restrict__ skel, int* __restrict__ cnt,
                  int* __restrict__ done, float* __restrict__ out) {
    __shared__ u64 P[SR2 * WPR];
    __shared__ u64 G[SR2 * WPR];
    __shared__ int acc[4];
    __shared__ int s_last;

    int b = blockIdx.x / STRIPS;
    int s = blockIdx.x % STRIPS;
    int tid = threadIdx.x;
    int r0 = s * SROWS - 3;

    const u64* sp = skel + (size_t)b * NWORDS;
    const u64* sg = skel + (size_t)(NB + b) * NWORDS;
    for (int i = tid; i < SR2 * WPR; i += 256) {
        int gr = r0 + (i >> 3);
        bool in = (gr >= 0 && gr < HH);
        int gi = gr * WPR + (i & 7);
        P[i] = in ? sp[gi] : 0ULL;
        G[i] = in ? sg[gi] : 0ULL;
    }
    if (tid < 4) acc[tid] = 0;
    __syncthreads();

    int cp = 0, cg = 0, tp = 0, fnh = 0;
    #pragma unroll
    for (int k = 0; k < 2; ++k) {
        int w = k * 256 + tid;
        int r = (w >> 3) + 3, c = w & 7;
        u64 pw = P[r * WPR + c], gw = G[r * WPR + c];
        cp  += __popcll(pw);
        cg  += __popcll(gw);
        tp  += __popcll(pw & dil3s(G, r, c));
        fnh += __popcll(gw & dil3s(P, r, c));
    }
    #pragma unroll
    for (int o = 32; o > 0; o >>= 1) {
        cp  += __shfl_down(cp, o);
        cg  += __shfl_down(cg, o);
        tp  += __shfl_down(tp, o);
        fnh += __shfl_down(fnh, o);
    }
    if ((tid & 63) == 0) {
        atomicAdd(&acc[0], cp);
        atomicAdd(&acc[1], cg);
        atomicAdd(&acc[2], tp);
        atomicAdd(&acc[3], fnh);
    }
    __syncthreads();
    if (tid < 4) atomicAdd(&cnt[b * 4 + tid], acc[tid]);
    __syncthreads();
    if (tid == 0) {
        __threadfence();                       // release this block's counts
        s_last = (atomicAdd(done, 1) == NB * STRIPS - 1);
    }
    __syncthreads();
    if (!s_last) return;
    __threadfence();                           // acquire all counts

    if (tid < 3) {
        float sacc = 0.0f;
        for (int i = 0; i < NB; ++i) {
            float c0 = (float)atomicAdd(&cnt[i * 4 + 0], 0);
            float c1 = (float)atomicAdd(&cnt[i * 4 + 1], 0);
            float TP = (float)atomicAdd(&cnt[i * 4 + 2], 0);
            float c3 = (float)atomicAdd(&cnt[i * 4 + 3], 0);
            float FP = c0 - TP;
            float FN = c1 - c3;
            float v = (tid == 0) ? TP / (TP + FP + 1e-12f)
                    : (tid == 1) ? TP / (TP + FN + 1e-12f)
                                 : TP / (TP + FP + FN + 1e-12f);
            sacc += v;
        }
        out[tid] = sacc * (1.0f / NB);
    }
}

extern "C" void kernel_launch(void* const* d_in, const int* in_sizes, int n_in,
                              void* d_out, int out_size, void* d_ws, size_t ws_size,
                              hipStream_t stream) {
    (void)in_sizes; (void)n_in; (void)out_size; (void)ws_size;
    const float* y_pred = (const float*)d_in[0];
    const float* y_true = (const float*)d_in[1];
    float* out = (float*)d_out;

    u64* buf0 = (u64*)d_ws;                               // 1 MB
    u64* buf1 = buf0 + (size_t)NIMG * NWORDS;             // 1 MB
    int* cnt = (int*)(buf1 + (size_t)NIMG * NWORDS);      // 64 ints
    int* flags = cnt + 4 * NB;                            // 32 ints
    int* done = flags + NIMG;                             // 1 int

    hipLaunchKernelGGL(pack_kernel, dim3(2 * NB * HW / 4 / 256), dim3(256), 0, stream,
                       y_pred, y_true, buf0, cnt);
    hipLaunchKernelGGL(strip_kernel, dim3(NIMG * SSTRIPS), dim3(STHREADS), 0, stream,
                       buf0, buf1, flags, 0);             // exact phases 1..16
    hipLaunchKernelGGL(strip_kernel, dim3(NIMG * SSTRIPS), dim3(STHREADS), 0, stream,
                       buf1, buf0, flags, 1);             // exact phases 17..32, record
    hipLaunchKernelGGL(skel_kernel, dim3(NIMG), dim3(NTHREADS), 0, stream,
                       buf0, flags);                      // fallback, skipped when converged
    hipLaunchKernelGGL(count_kernel, dim3(NB * STRIPS), dim3(256), 0, stream,
                       buf0, cnt, done, out);
}